// Round 5
// baseline (492.706 us; speedup 1.0000x reference)
//
#include <hip/hip_runtime.h>
#include <stdint.h>

#define T_STEPS 512
#define D_INP   32
#define CHUNK   8
#define NCHUNK  (T_STEPS / CHUNK)

typedef float f2 __attribute__((ext_vector_type(2)));
typedef float f4 __attribute__((ext_vector_type(4)));

typedef const uint32_t __attribute__((address_space(1)))* gas1_t;
typedef uint32_t __attribute__((address_space(3)))* las3_t;

#define LOG2E 1.44269504088896f
#define TANHK (-2.88539008177793f)   // -2*log2(e)

template <int K>
__device__ __forceinline__ float qbcast(float v) {
  // broadcast lane (quad_base + K) to all 4 lanes of each quad (VALU pipe)
  return __int_as_float(
      __builtin_amdgcn_mov_dpp(__float_as_int(v), K * 85, 0xF, 0xF, true));
}

__device__ __forceinline__ float frcp(float v) { return __builtin_amdgcn_rcpf(v); }
__device__ __forceinline__ float fexp2(float v) { return __builtin_amdgcn_exp2f(v); }
__device__ __forceinline__ f2 lo2(f4 v) { return __builtin_shufflevector(v, v, 0, 1); }
__device__ __forceinline__ f2 hi2(f4 v) { return __builtin_shufflevector(v, v, 2, 3); }
__device__ __forceinline__ f2 pkfma(f2 a, f2 b, f2 c) {
  return __builtin_elementwise_fma(a, b, c);   // v_pk_fma_f32
}

// Layer-pipelined 2-wave block: wave0 runs layer 0, wave1 runs layer 1 one
// 8-step chunk behind, h0 passed through a double-buffered LDS ring.
// 4096 blocks x 128 thr = 8192 waves = 8 waves/SIMD (vs 4 before): the
// point is latency hiding — real VALU busy was ~35% (VALUBusy derived
// metric over-reads 2x on gfx950; gfx94x SIMD-16 formula).
extern "C" __global__ void __launch_bounds__(128)
lstm2_pipe(const float* __restrict__ x,
           const float* __restrict__ Wih0, const float* __restrict__ Whh0,
           const float* __restrict__ bih0, const float* __restrict__ bhh0,
           const float* __restrict__ Wih1, const float* __restrict__ Whh1,
           const float* __restrict__ bih1, const float* __restrict__ bhh1,
           const float* __restrict__ fc1w, const float* __restrict__ fc1b,
           const float* __restrict__ fc2w, const float* __restrict__ fc2b,
           float* __restrict__ out)
{
  __shared__ __align__(16) float lx[2][CHUNK * D_INP];   // 2KB x staging (wave0)
  __shared__ __align__(16) float ring[2][CHUNK][16];     // 1KB h0 ring w0 -> w1
  __shared__ __align__(16) float dump[64];               // compact-write spill
  __shared__ __align__(16) float lh1[80];                // wave1 h1 round-trip

  const int tid  = threadIdx.x;
  const int w    = tid >> 6;
  const int lane = tid & 63;
  const int b    = blockIdx.x;

  const int k   = lane & 3;      // gate: 0=i 1=f 2=g(tanh) 3=o
  const int u   = lane >> 2;     // hidden unit 0..15
  const int row = k * 16 + u;

  const float sc = (k == 2) ? -2.0f * LOG2E : -LOG2E;
  const float mA = (k == 2) ?  2.0f : 1.0f;
  const float aA = (k == 2) ? -1.0f : 0.0f;

  if (w == 0) {
    // ================= producer: layer 0 =================
    f2 wi0[16], wh0[8];
    {
      const f4* p = (const f4*)(Wih0 + row * 32);
#pragma unroll
      for (int q = 0; q < 8; ++q) {
        f4 v = p[q];
        wi0[2 * q + 0] = lo2(v) * sc;
        wi0[2 * q + 1] = hi2(v) * sc;
      }
      const f4* p0 = (const f4*)(Whh0 + row * 16);
#pragma unroll
      for (int q = 0; q < 4; ++q) {
        f4 a = p0[q];
        wh0[2 * q] = lo2(a) * sc;  wh0[2 * q + 1] = hi2(a) * sc;
      }
    }
    const float bs0 = sc * (bih0[row] + bhh0[row]);
    float c0 = 0.f;
    if (lane < 16) ring[1][CHUNK - 1][lane] = 0.f;   // h0[t=-1] = 0

    const float* xg = x + (size_t)b * (T_STEPS * D_INP);
    {
      const float* src = xg + lane * 4;
      __builtin_amdgcn_global_load_lds((gas1_t)(const void*)src,
                                       (las3_t)(void*)&lx[0][0], 16, 0, 0);
    }

#pragma unroll 1
    for (int c = 0; c <= NCHUNK; ++c) {
      if (c < NCHUNK) {
        asm volatile("s_waitcnt vmcnt(0)" ::: "memory");
        if (c + 1 < NCHUNK) {
          const float* src = xg + (c + 1) * (CHUNK * D_INP) + lane * 4;
          __builtin_amdgcn_global_load_lds((gas1_t)(const void*)src,
                                           (las3_t)(void*)&lx[(c + 1) & 1][0],
                                           16, 0, 0);
        }
        const float* xp = &lx[c & 1][0];
        const int h = c & 1;
#pragma unroll
        for (int tt = 0; tt < CHUNK; ++tt) {
          const float* xq = xp + tt * D_INP;
          const float* hp = (tt == 0) ? &ring[h ^ 1][CHUNK - 1][0]
                                      : &ring[h][tt - 1][0];
          f2 A = (f2){bs0, 0.f}, B = (f2){0.f, 0.f};
          f2 C = (f2){0.f, 0.f}, D = (f2){0.f, 0.f};
#pragma unroll
          for (int q = 0; q < 4; ++q) {          // x[0:16)
            f4 v = *(const f4*)(xq + 4 * q);
            A = pkfma(wi0[2 * q + 0], lo2(v), A);
            B = pkfma(wi0[2 * q + 1], hi2(v), B);
          }
#pragma unroll
          for (int q = 4; q < 8; ++q) {          // x[16:32)
            f4 v = *(const f4*)(xq + 4 * q);
            C = pkfma(wi0[2 * q + 0], lo2(v), C);
            D = pkfma(wi0[2 * q + 1], hi2(v), D);
          }
#pragma unroll
          for (int q = 0; q < 2; ++q) {          // h0[0:8)
            f4 hv = *(const f4*)(hp + 4 * q);
            A = pkfma(wh0[2 * q + 0], lo2(hv), A);
            B = pkfma(wh0[2 * q + 1], hi2(hv), B);
          }
#pragma unroll
          for (int q = 2; q < 4; ++q) {          // h0[8:16)
            f4 hv = *(const f4*)(hp + 4 * q);
            C = pkfma(wh0[2 * q + 0], lo2(hv), C);
            D = pkfma(wh0[2 * q + 1], hi2(hv), D);
          }
          f2 s = (A + B) + (C + D);
          float gs = s.x + s.y;
          float av = fmaf(mA, frcp(1.f + fexp2(gs)), aA);
          float fv = qbcast<1>(av), gv = qbcast<2>(av), ov = qbcast<3>(av);
          c0 = fmaf(fv, c0, av * gv);
          float th = fmaf(2.f, frcp(1.f + fexp2(TANHK * c0)), -1.f);
          float h0n = ov * th;
          float* dst = (k == 0) ? &ring[h][tt][u] : &dump[lane];
          *dst = h0n;
        }
      }
      __syncthreads();
    }
  } else {
    // ================= consumer: layer 1 (lags one chunk) =================
    f2 wi1[8], wh1[8];
    {
      const f4* p1 = (const f4*)(Wih1 + row * 16);
      const f4* p2 = (const f4*)(Whh1 + row * 16);
#pragma unroll
      for (int q = 0; q < 4; ++q) {
        f4 bq = p1[q], cq = p2[q];
        wi1[2 * q] = lo2(bq) * sc; wi1[2 * q + 1] = hi2(bq) * sc;
        wh1[2 * q] = lo2(cq) * sc; wh1[2 * q + 1] = hi2(cq) * sc;
      }
    }
    const float bs1 = sc * (bih1[row] + bhh1[row]);
    const int slot = (k == 0) ? u : (16 + lane);
    float* h1slot = &lh1[slot];
    float c1 = 0.f;
    if (lane < 16) lh1[lane] = 0.f;   // h1[t=-1] = 0

#pragma unroll 1
    for (int c = 0; c <= NCHUNK; ++c) {
      if (c >= 1) {
        const int h = (c - 1) & 1;
#pragma unroll
        for (int tt = 0; tt < CHUNK; ++tt) {
          const float* hb = &ring[h][tt][0];     // h0[t] from producer
          f4 g0 = *(const f4*)(hb + 0);
          f4 g1 = *(const f4*)(hb + 4);
          f4 g2 = *(const f4*)(hb + 8);
          f4 g3 = *(const f4*)(hb + 12);
          f4 e0 = *(const f4*)(&lh1[0]);         // h1[t-1]
          f4 e1 = *(const f4*)(&lh1[4]);
          f4 e2 = *(const f4*)(&lh1[8]);
          f4 e3 = *(const f4*)(&lh1[12]);
          f2 A = (f2){bs1, 0.f}, B = (f2){0.f, 0.f};
          f2 C = (f2){0.f, 0.f}, D = (f2){0.f, 0.f};
          A = pkfma(wi1[0], lo2(g0), A);  B = pkfma(wi1[1], hi2(g0), B);
          A = pkfma(wi1[2], lo2(g1), A);  B = pkfma(wi1[3], hi2(g1), B);
          C = pkfma(wi1[4], lo2(g2), C);  D = pkfma(wi1[5], hi2(g2), D);
          C = pkfma(wi1[6], lo2(g3), C);  D = pkfma(wi1[7], hi2(g3), D);
          A = pkfma(wh1[0], lo2(e0), A);  B = pkfma(wh1[1], hi2(e0), B);
          A = pkfma(wh1[2], lo2(e1), A);  B = pkfma(wh1[3], hi2(e1), B);
          C = pkfma(wh1[4], lo2(e2), C);  D = pkfma(wh1[5], hi2(e2), D);
          C = pkfma(wh1[6], lo2(e3), C);  D = pkfma(wh1[7], hi2(e3), D);
          f2 s = (A + B) + (C + D);
          float gs1 = s.x + s.y;
          float av1 = fmaf(mA, frcp(1.f + fexp2(gs1)), aA);
          float fv1 = qbcast<1>(av1), gv1 = qbcast<2>(av1), ov1 = qbcast<3>(av1);
          c1 = fmaf(fv1, c1, av1 * gv1);
          float th1 = fmaf(2.f, frcp(1.f + fexp2(TANHK * c1)), -1.f);
          float h1n = ov1 * th1;
          *h1slot = h1n;
        }
      }
      __syncthreads();
    }

    // ======== head: y = relu(h1_T @ fc1^T + b1) @ fc2^T + b2 ========
    float h1f[16];
#pragma unroll
    for (int q = 0; q < 4; ++q) {
      f4 hv = *(const f4*)(&lh1[4 * q]);
#pragma unroll
      for (int r = 0; r < 4; ++r) h1f[4 * q + r] = hv[r];
    }
    float rr = 0.f;
    if (lane < 8) {
      float acc = fc1b[lane];
#pragma unroll
      for (int j = 0; j < 16; ++j) acc = fmaf(fc1w[lane * 16 + j], h1f[j], acc);
      rr = fmaxf(acc, 0.f) * fc2w[lane];
    }
    rr += __shfl_xor(rr, 1, 64);
    rr += __shfl_xor(rr, 2, 64);
    rr += __shfl_xor(rr, 4, 64);
    if (lane == 0) out[b] = rr + fc2b[0];
  }
}

extern "C" void kernel_launch(void* const* d_in, const int* in_sizes, int n_in,
                              void* d_out, int out_size, void* d_ws, size_t ws_size,
                              hipStream_t stream) {
  (void)in_sizes; (void)n_in; (void)d_ws; (void)ws_size; (void)out_size;
  const float* x    = (const float*)d_in[0];
  const float* Wih0 = (const float*)d_in[1];
  const float* Whh0 = (const float*)d_in[2];
  const float* bih0 = (const float*)d_in[3];
  const float* bhh0 = (const float*)d_in[4];
  const float* Wih1 = (const float*)d_in[5];
  const float* Whh1 = (const float*)d_in[6];
  const float* bih1 = (const float*)d_in[7];
  const float* bhh1 = (const float*)d_in[8];
  const float* fc1w = (const float*)d_in[9];
  const float* fc1b = (const float*)d_in[10];
  const float* fc2w = (const float*)d_in[11];
  const float* fc2b = (const float*)d_in[12];
  lstm2_pipe<<<dim3(4096), dim3(128), 0, stream>>>(
      x, Wih0, Whh0, bih0, bhh0, Wih1, Whh1, bih1, bhh1,
      fc1w, fc1b, fc2w, fc2b, (float*)d_out);
}

// Round 6
// 491.565 us; speedup vs baseline: 1.0023x; 1.0023x over previous
//
#include <hip/hip_runtime.h>
#include <stdint.h>

#define T_STEPS 512
#define D_INP   32

typedef float f2 __attribute__((ext_vector_type(2)));
typedef float f4 __attribute__((ext_vector_type(4)));

#define LOG2E 1.44269504088896f
#define TANHK (-2.88539008177793f)   // -2*log2(e)

template <int K>
__device__ __forceinline__ float qbcast(float v) {
  // broadcast lane (quad_base + K) to all 4 lanes of each quad (VALU pipe)
  return __int_as_float(
      __builtin_amdgcn_mov_dpp(__float_as_int(v), K * 85, 0xF, 0xF, true));
}
__device__ __forceinline__ float frcp(float v) { return __builtin_amdgcn_rcpf(v); }
__device__ __forceinline__ float fexp2(float v) { return __builtin_amdgcn_exp2f(v); }
__device__ __forceinline__ f2 lo2(f4 v) { return __builtin_shufflevector(v, v, 0, 1); }
__device__ __forceinline__ f2 hi2(f4 v) { return __builtin_shufflevector(v, v, 2, 3); }
__device__ __forceinline__ f2 pkfma(f2 a, f2 b, f2 c) {
  return __builtin_elementwise_fma(a, b, c);   // v_pk_fma_f32
}
__device__ __forceinline__ float rlane(float v, int l) {
  // explicit-index cross-lane read -> SGPR; direction-unambiguous
  return __int_as_float(__builtin_amdgcn_readlane(__float_as_int(v), l));
}

// Zero-LDS design. Previous kernels were DS-pipe-bound (~16KB LDS return
// traffic per step per wave; 256B/clk bus x 16 waves/CU ~= the measured
// 2133 cyc/step wall). Here: 64-thread blocks make b=blockIdx.x uniform so
// x loads are wave-uniform (scalar path); h state is broadcast through
// v_readlane into SGPRs and consumed as the scalar operand of v_fma.
// No __shared__, no barriers, no DS instructions in the hot loop.
extern "C" __global__ void __launch_bounds__(64)
lstm2_rl(const float* __restrict__ x,
         const float* __restrict__ Wih0, const float* __restrict__ Whh0,
         const float* __restrict__ bih0, const float* __restrict__ bhh0,
         const float* __restrict__ Wih1, const float* __restrict__ Whh1,
         const float* __restrict__ bih1, const float* __restrict__ bhh1,
         const float* __restrict__ fc1w, const float* __restrict__ fc1b,
         const float* __restrict__ fc2w, const float* __restrict__ fc2b,
         float* __restrict__ out)
{
  const int lane = threadIdx.x;      // 0..63
  const int b    = blockIdx.x;       // uniform per wave
  const int k    = lane & 3;         // gate: 0=i 1=f 2=g(tanh) 3=o
  const int u    = lane >> 2;        // hidden unit 0..15
  const int row  = k * 16 + u;

  // prescale so activation is exp2-based
  const float sc = (k == 2) ? -2.0f * LOG2E : -LOG2E;
  const float mA = (k == 2) ?  2.0f : 1.0f;
  const float aA = (k == 2) ? -1.0f : 0.0f;

  // per-lane weights (prescaled)
  f2 wi0[16];
  float wh0[16], wi1[16], wh1[16];
  {
    const f4* p = (const f4*)(Wih0 + row * 32);
#pragma unroll
    for (int q = 0; q < 8; ++q) {
      f4 v = p[q];
      wi0[2 * q + 0] = lo2(v) * sc;
      wi0[2 * q + 1] = hi2(v) * sc;
    }
#pragma unroll
    for (int j = 0; j < 16; ++j) {
      wh0[j] = sc * Whh0[row * 16 + j];
      wi1[j] = sc * Wih1[row * 16 + j];
      wh1[j] = sc * Whh1[row * 16 + j];
    }
  }
  const float bs0 = sc * (bih0[row] + bhh0[row]);
  const float bs1 = sc * (bih1[row] + bhh1[row]);

  float c0 = 0.f, c1 = 0.f;
  float h0s[16], h1s[16];            // uniform (SGPR) copies of h state
#pragma unroll
  for (int j = 0; j < 16; ++j) { h0s[j] = 0.f; h1s[j] = 0.f; }

  const float* xb = x + (size_t)b * (T_STEPS * D_INP);

#pragma unroll 4
  for (int t = 0; t < T_STEPS; ++t) {
    const f4* xq = (const f4*)(xb + t * D_INP);   // uniform address
    // ======== layer 0 ========
    f2 a01 = (f2){bs0, 0.f}, a23 = (f2){0.f, 0.f};
#pragma unroll
    for (int q = 0; q < 8; ++q) {
      f4 v = xq[q];
      a01 = pkfma(wi0[2 * q + 0], lo2(v), a01);
      a23 = pkfma(wi0[2 * q + 1], hi2(v), a23);
    }
#pragma unroll
    for (int j = 0; j < 16; j += 4) {   // Whh0 . h0 (h from SGPRs)
      a01.x = fmaf(wh0[j + 0], h0s[j + 0], a01.x);
      a01.y = fmaf(wh0[j + 1], h0s[j + 1], a01.y);
      a23.x = fmaf(wh0[j + 2], h0s[j + 2], a23.x);
      a23.y = fmaf(wh0[j + 3], h0s[j + 3], a23.y);
    }
    f2 s = a01 + a23;
    float gs = s.x + s.y;
    float av = fmaf(mA, frcp(1.f + fexp2(gs)), aA);
    // own av serves as gate k; only k==0 lanes' h is ever read back
    float fv = qbcast<1>(av), gv = qbcast<2>(av), ov = qbcast<3>(av);
    c0 = fmaf(fv, c0, av * gv);
    float th = fmaf(2.f, frcp(1.f + fexp2(TANHK * c0)), -1.f);
    float h0n = ov * th;
#pragma unroll
    for (int j = 0; j < 16; ++j) h0s[j] = rlane(h0n, 4 * j);

    // ======== layer 1 ========
    f2 b01 = (f2){bs1, 0.f}, b23 = (f2){0.f, 0.f};
#pragma unroll
    for (int j = 0; j < 16; j += 4) {   // Wih1 . h0
      b01.x = fmaf(wi1[j + 0], h0s[j + 0], b01.x);
      b01.y = fmaf(wi1[j + 1], h0s[j + 1], b01.y);
      b23.x = fmaf(wi1[j + 2], h0s[j + 2], b23.x);
      b23.y = fmaf(wi1[j + 3], h0s[j + 3], b23.y);
    }
#pragma unroll
    for (int j = 0; j < 16; j += 4) {   // Whh1 . h1
      b01.x = fmaf(wh1[j + 0], h1s[j + 0], b01.x);
      b01.y = fmaf(wh1[j + 1], h1s[j + 1], b01.y);
      b23.x = fmaf(wh1[j + 2], h1s[j + 2], b23.x);
      b23.y = fmaf(wh1[j + 3], h1s[j + 3], b23.y);
    }
    f2 s1 = b01 + b23;
    float gs1 = s1.x + s1.y;
    float av1 = fmaf(mA, frcp(1.f + fexp2(gs1)), aA);
    float fv1 = qbcast<1>(av1), gv1 = qbcast<2>(av1), ov1 = qbcast<3>(av1);
    c1 = fmaf(fv1, c1, av1 * gv1);
    float th1 = fmaf(2.f, frcp(1.f + fexp2(TANHK * c1)), -1.f);
    float h1n = ov1 * th1;
#pragma unroll
    for (int j = 0; j < 16; ++j) h1s[j] = rlane(h1n, 4 * j);
  }

  // ======== head: y = relu(h1_T @ fc1^T + b1) @ fc2^T + b2 ========
  float rr = 0.f;
  if (lane < 8) {
    float acc = fc1b[lane];
#pragma unroll
    for (int j = 0; j < 16; ++j) acc = fmaf(fc1w[lane * 16 + j], h1s[j], acc);
    rr = fmaxf(acc, 0.f) * fc2w[lane];
  }
  rr += __shfl_xor(rr, 1, 64);
  rr += __shfl_xor(rr, 2, 64);
  rr += __shfl_xor(rr, 4, 64);
  if (lane == 0) out[b] = rr + fc2b[0];
}

extern "C" void kernel_launch(void* const* d_in, const int* in_sizes, int n_in,
                              void* d_out, int out_size, void* d_ws, size_t ws_size,
                              hipStream_t stream) {
  (void)in_sizes; (void)n_in; (void)d_ws; (void)ws_size; (void)out_size;
  const float* x    = (const float*)d_in[0];
  const float* Wih0 = (const float*)d_in[1];
  const float* Whh0 = (const float*)d_in[2];
  const float* bih0 = (const float*)d_in[3];
  const float* bhh0 = (const float*)d_in[4];
  const float* Wih1 = (const float*)d_in[5];
  const float* Whh1 = (const float*)d_in[6];
  const float* bih1 = (const float*)d_in[7];
  const float* bhh1 = (const float*)d_in[8];
  const float* fc1w = (const float*)d_in[9];
  const float* fc1b = (const float*)d_in[10];
  const float* fc2w = (const float*)d_in[11];
  const float* fc2b = (const float*)d_in[12];
  lstm2_rl<<<dim3(4096), dim3(64), 0, stream>>>(
      x, Wih0, Whh0, bih0, bhh0, Wih1, Whh1, bih1, bhh1,
      fc1w, fc1b, fc2w, fc2b, (float*)d_out);
}

// Round 7
// 459.359 us; speedup vs baseline: 1.0726x; 1.0701x over previous
//
#include <hip/hip_runtime.h>
#include <stdint.h>

#define T_STEPS 512
#define D_INP   32
#define CHUNK   8
#define NCHUNK  (T_STEPS / CHUNK)
#define ELEMS   2

typedef float f2 __attribute__((ext_vector_type(2)));
typedef float f4 __attribute__((ext_vector_type(4)));

typedef const uint32_t __attribute__((address_space(1)))* gas1_t;
typedef uint32_t __attribute__((address_space(3)))* las3_t;

#define LOG2E 1.44269504088896f
#define TANHK (-2.88539008177793f)   // -2*log2(e)

template <int K>
__device__ __forceinline__ float qbcast(float v) {
  // broadcast lane (quad_base + K) to all 4 lanes of each quad (VALU pipe)
  return __int_as_float(
      __builtin_amdgcn_mov_dpp(__float_as_int(v), K * 85, 0xF, 0xF, true));
}
__device__ __forceinline__ float frcp(float v) { return __builtin_amdgcn_rcpf(v); }
__device__ __forceinline__ float fexp2(float v) { return __builtin_amdgcn_exp2f(v); }
__device__ __forceinline__ f2 lo2(f4 v) { return __builtin_shufflevector(v, v, 0, 1); }
__device__ __forceinline__ f2 hi2(f4 v) { return __builtin_shufflevector(v, v, 2, 3); }
__device__ __forceinline__ f2 pkfma(f2 a, f2 b, f2 c) {
  return __builtin_elementwise_fma(a, b, c);   // v_pk_fma_f32
}

// E=2 batch elements per wave. R1-R6 invariant: wall ~2100-2300 cyc/step/SIMD
// with real VALU busy ~35% regardless of LDS vs readlane vs wave-pipelining:
// 4 waves/SIMD each carrying ONE serial recurrence cannot hide the per-step
// latency chain. Weights are shared between the 2 elements (same lane->row
// mapping); only state duplicates. Interleave A-L0, B-L0, A-L1, B-L1 so each
// element's LDS h round-trip hides under the other's compute.
extern "C" __global__ void __launch_bounds__(256)
__attribute__((amdgpu_waves_per_eu(2, 2)))
lstm2_e2(const float* __restrict__ x,
         const float* __restrict__ Wih0, const float* __restrict__ Whh0,
         const float* __restrict__ bih0, const float* __restrict__ bhh0,
         const float* __restrict__ Wih1, const float* __restrict__ Whh1,
         const float* __restrict__ bih1, const float* __restrict__ bhh1,
         const float* __restrict__ fc1w, const float* __restrict__ fc1b,
         const float* __restrict__ fc2w, const float* __restrict__ fc2b,
         float* __restrict__ out)
{
  __shared__ __align__(16) float lx[4][ELEMS][2][CHUNK * D_INP]; // 16KB
  __shared__ __align__(16) float lh0[4][ELEMS][80];              // 2.5KB
  __shared__ __align__(16) float lh1[4][ELEMS][80];              // 2.5KB

  const int tid  = threadIdx.x;
  const int w    = tid >> 6;
  const int lane = tid & 63;
  const int base = blockIdx.x * (4 * ELEMS) + w * ELEMS;

  const int k   = lane & 3;      // gate: 0=i 1=f 2=g(tanh) 3=o
  const int u   = lane >> 2;     // hidden unit 0..15
  const int row = k * 16 + u;

  const float sc = (k == 2) ? -2.0f * LOG2E : -LOG2E;
  const float mA = (k == 2) ?  2.0f : 1.0f;
  const float aA = (k == 2) ? -1.0f : 0.0f;

  // ---- weights: SHARED by both elements (one copy, ~80 VGPRs) ----
  f2 wi0[16], wh0[8], wi1[8], wh1[8];
  {
    const f4* p = (const f4*)(Wih0 + row * 32);
#pragma unroll
    for (int q = 0; q < 8; ++q) {
      f4 v = p[q];
      wi0[2 * q + 0] = lo2(v) * sc;
      wi0[2 * q + 1] = hi2(v) * sc;
    }
    const f4* p0 = (const f4*)(Whh0 + row * 16);
    const f4* p1 = (const f4*)(Wih1 + row * 16);
    const f4* p2 = (const f4*)(Whh1 + row * 16);
#pragma unroll
    for (int q = 0; q < 4; ++q) {
      f4 a = p0[q], bq = p1[q], cq = p2[q];
      wh0[2 * q] = lo2(a) * sc;  wh0[2 * q + 1] = hi2(a) * sc;
      wi1[2 * q] = lo2(bq) * sc; wi1[2 * q + 1] = hi2(bq) * sc;
      wh1[2 * q] = lo2(cq) * sc; wh1[2 * q + 1] = hi2(cq) * sc;
    }
  }
  const float bs0 = sc * (bih0[row] + bhh0[row]);
  const float bs1 = sc * (bih1[row] + bhh1[row]);

  const int slot = (k == 0) ? u : (16 + lane);

  // ---- per-element state ----
  float c0[ELEMS], c1[ELEMS];
  f2 h0p[ELEMS][8];
  float* h0slot[ELEMS];
  float* h1slot[ELEMS];
  const float* xg[ELEMS];
#pragma unroll
  for (int e = 0; e < ELEMS; ++e) {
    c0[e] = 0.f; c1[e] = 0.f;
#pragma unroll
    for (int j = 0; j < 8; ++j) h0p[e][j] = (f2){0.f, 0.f};
    h0slot[e] = &lh0[w][e][slot];
    h1slot[e] = &lh1[w][e][slot];
    if (lane < 16) lh1[w][e][lane] = 0.f;   // h1[t=-1] = 0
    xg[e] = x + (size_t)(base + e) * (T_STEPS * D_INP);
    const float* src = xg[e] + lane * 4;
    __builtin_amdgcn_global_load_lds((gas1_t)(const void*)src,
                                     (las3_t)(void*)&lx[w][e][0][0], 16, 0, 0);
  }

#pragma unroll 1
  for (int c = 0; c < NCHUNK; ++c) {
    asm volatile("s_waitcnt vmcnt(0)" ::: "memory");
    if (c + 1 < NCHUNK) {
#pragma unroll
      for (int e = 0; e < ELEMS; ++e) {
        const float* src = xg[e] + (c + 1) * (CHUNK * D_INP) + lane * 4;
        __builtin_amdgcn_global_load_lds((gas1_t)(const void*)src,
                                         (las3_t)(void*)&lx[w][e][(c + 1) & 1][0],
                                         16, 0, 0);
      }
    }
#pragma unroll
    for (int tt = 0; tt < CHUNK; ++tt) {
      // ---- hoisted: h1[t-1] reads + Whh1 partials, both elems ----
      f2 b01[ELEMS], b23[ELEMS];
#pragma unroll
      for (int e = 0; e < ELEMS; ++e) {
        f4 hA = *(const f4*)(&lh1[w][e][0]);
        f4 hB = *(const f4*)(&lh1[w][e][4]);
        f4 hC = *(const f4*)(&lh1[w][e][8]);
        f4 hD = *(const f4*)(&lh1[w][e][12]);
        f2 p01 = (f2){bs1, 0.f}, p23 = (f2){0.f, 0.f};
        p01 = pkfma(wh1[0], lo2(hA), p01);  p23 = pkfma(wh1[1], hi2(hA), p23);
        p01 = pkfma(wh1[2], lo2(hB), p01);  p23 = pkfma(wh1[3], hi2(hB), p23);
        p01 = pkfma(wh1[4], lo2(hC), p01);  p23 = pkfma(wh1[5], hi2(hC), p23);
        p01 = pkfma(wh1[6], lo2(hD), p01);  p23 = pkfma(wh1[7], hi2(hD), p23);
        b01[e] = p01; b23[e] = p23;
      }
      // ---- layer 0, both elems (A fully, then B: B's block hides A's write) ----
#pragma unroll
      for (int e = 0; e < ELEMS; ++e) {
        const float* xq = &lx[w][e][c & 1][tt * D_INP];
        f2 a01 = (f2){bs0, 0.f}, a23 = (f2){0.f, 0.f};
#pragma unroll
        for (int q = 0; q < 8; ++q) {
          f4 v = *(const f4*)(xq + 4 * q);
          a01 = pkfma(wi0[2 * q + 0], lo2(v), a01);
          a23 = pkfma(wi0[2 * q + 1], hi2(v), a23);
        }
#pragma unroll
        for (int q = 0; q < 4; ++q) {
          a01 = pkfma(wh0[2 * q + 0], h0p[e][2 * q + 0], a01);
          a23 = pkfma(wh0[2 * q + 1], h0p[e][2 * q + 1], a23);
        }
        f2 s = a01 + a23;
        float gs = s.x + s.y;
        float av = fmaf(mA, frcp(1.f + fexp2(gs)), aA);
        float fv = qbcast<1>(av), gv = qbcast<2>(av), ov = qbcast<3>(av);
        c0[e] = fmaf(fv, c0[e], av * gv);
        float th = fmaf(2.f, frcp(1.f + fexp2(TANHK * c0[e])), -1.f);
        *h0slot[e] = ov * th;
      }
      // ---- reload h0 broadcast + layer 1 tail, both elems ----
#pragma unroll
      for (int e = 0; e < ELEMS; ++e) {
#pragma unroll
        for (int q = 0; q < 4; ++q) {
          f4 hv = *(const f4*)(&lh0[w][e][4 * q]);
          h0p[e][2 * q + 0] = lo2(hv);
          h0p[e][2 * q + 1] = hi2(hv);
        }
        f2 p01 = b01[e], p23 = b23[e];
#pragma unroll
        for (int q = 0; q < 4; ++q) {
          p01 = pkfma(wi1[2 * q + 0], h0p[e][2 * q + 0], p01);
          p23 = pkfma(wi1[2 * q + 1], h0p[e][2 * q + 1], p23);
        }
        f2 s1 = p01 + p23;
        float gs1 = s1.x + s1.y;
        float av1 = fmaf(mA, frcp(1.f + fexp2(gs1)), aA);
        float fv1 = qbcast<1>(av1), gv1 = qbcast<2>(av1), ov1 = qbcast<3>(av1);
        c1[e] = fmaf(fv1, c1[e], av1 * gv1);
        float th1 = fmaf(2.f, frcp(1.f + fexp2(TANHK * c1[e])), -1.f);
        *h1slot[e] = ov1 * th1;
      }
    }
  }

  // ======== head: y = relu(h1_T @ fc1^T + b1) @ fc2^T + b2 ========
#pragma unroll
  for (int e = 0; e < ELEMS; ++e) {
    float h1f[16];
#pragma unroll
    for (int q = 0; q < 4; ++q) {
      f4 hv = *(const f4*)(&lh1[w][e][4 * q]);
#pragma unroll
      for (int r = 0; r < 4; ++r) h1f[4 * q + r] = hv[r];
    }
    float rr = 0.f;
    if (lane < 8) {
      float acc = fc1b[lane];
#pragma unroll
      for (int j = 0; j < 16; ++j) acc = fmaf(fc1w[lane * 16 + j], h1f[j], acc);
      rr = fmaxf(acc, 0.f) * fc2w[lane];
    }
    rr += __shfl_xor(rr, 1, 64);
    rr += __shfl_xor(rr, 2, 64);
    rr += __shfl_xor(rr, 4, 64);
    if (lane == 0) out[base + e] = rr + fc2b[0];
  }
}

extern "C" void kernel_launch(void* const* d_in, const int* in_sizes, int n_in,
                              void* d_out, int out_size, void* d_ws, size_t ws_size,
                              hipStream_t stream) {
  (void)in_sizes; (void)n_in; (void)d_ws; (void)ws_size; (void)out_size;
  const float* x    = (const float*)d_in[0];
  const float* Wih0 = (const float*)d_in[1];
  const float* Whh0 = (const float*)d_in[2];
  const float* bih0 = (const float*)d_in[3];
  const float* bhh0 = (const float*)d_in[4];
  const float* Wih1 = (const float*)d_in[5];
  const float* Whh1 = (const float*)d_in[6];
  const float* bih1 = (const float*)d_in[7];
  const float* bhh1 = (const float*)d_in[8];
  const float* fc1w = (const float*)d_in[9];
  const float* fc1b = (const float*)d_in[10];
  const float* fc2w = (const float*)d_in[11];
  const float* fc2b = (const float*)d_in[12];
  lstm2_e2<<<dim3(512), dim3(256), 0, stream>>>(
      x, Wih0, Whh0, bih0, bhh0, Wih1, Whh1, bih1, bhh1,
      fc1w, fc1b, fc2w, fc2b, (float*)d_out);
}

// Round 8
// 417.860 us; speedup vs baseline: 1.1791x; 1.0993x over previous
//
#include <hip/hip_runtime.h>
#include <stdint.h>

#define T_STEPS 512
#define D_INP   32
#define CHUNK   8
#define NCHUNK  (T_STEPS / CHUNK)

typedef float f2 __attribute__((ext_vector_type(2)));
typedef float f4 __attribute__((ext_vector_type(4)));

typedef const uint32_t __attribute__((address_space(1)))* gas1_t;
typedef uint32_t __attribute__((address_space(3)))* las3_t;

#define LOG2E 1.44269504088896f
#define TANHK (-2.88539008177793f)   // -2*log2(e)

template <int K>
__device__ __forceinline__ float qbcast(float v) {
  // broadcast lane (quad_base + K) to all 4 lanes of each quad (VALU pipe)
  return __int_as_float(
      __builtin_amdgcn_mov_dpp(__float_as_int(v), K * 85, 0xF, 0xF, true));
}
__device__ __forceinline__ float frcp(float v) { return __builtin_amdgcn_rcpf(v); }
__device__ __forceinline__ float fexp2(float v) { return __builtin_amdgcn_exp2f(v); }
__device__ __forceinline__ f2 lo2(f4 v) { return __builtin_shufflevector(v, v, 0, 1); }
__device__ __forceinline__ f2 hi2(f4 v) { return __builtin_shufflevector(v, v, 2, 3); }

// FORCED packed fp32 math. __builtin_elementwise_fma on <2 x float> appears
// to scalarize (2x v_fma_f32 + movs): measured instr/step ~186 vs ~74 static
// across R1-R7 — the kernel has been VALU-issue-bound on scalar FMAs all
// along. Inline asm guarantees v_pk_fma_f32 (default op_sel = elementwise).
__device__ __forceinline__ void pkfma(f2& acc, f2 a, f2 b) {
  asm("v_pk_fma_f32 %0, %1, %2, %0" : "+v"(acc) : "v"(a), "v"(b));
}
__device__ __forceinline__ f2 pkadd(f2 a, f2 b) {
  f2 d;
  asm("v_pk_add_f32 %0, %1, %2" : "=v"(d) : "v"(a), "v"(b));
  return d;
}

extern "C" __global__ void __launch_bounds__(256)
lstm2_pk(const float* __restrict__ x,
         const float* __restrict__ Wih0, const float* __restrict__ Whh0,
         const float* __restrict__ bih0, const float* __restrict__ bhh0,
         const float* __restrict__ Wih1, const float* __restrict__ Whh1,
         const float* __restrict__ bih1, const float* __restrict__ bhh1,
         const float* __restrict__ fc1w, const float* __restrict__ fc1b,
         const float* __restrict__ fc2w, const float* __restrict__ fc2b,
         float* __restrict__ out)
{
  __shared__ __align__(16) float lx[4][2][CHUNK * D_INP]; // 8KB: x staging, dbuf
  __shared__ __align__(16) float lh0[4][80];              // [0:16) h0, [16:80) dump
  __shared__ __align__(16) float lh1[4][80];

  const int tid  = threadIdx.x;
  const int w    = tid >> 6;
  const int lane = tid & 63;
  const int b    = (blockIdx.x << 2) + w;

  const int k   = lane & 3;      // gate: 0=i 1=f 2=g(tanh) 3=o
  const int u   = lane >> 2;     // hidden unit 0..15
  const int row = k * 16 + u;

  const float sc = (k == 2) ? -2.0f * LOG2E : -LOG2E;
  const float mA = (k == 2) ?  2.0f : 1.0f;
  const float aA = (k == 2) ? -1.0f : 0.0f;

  // ---- per-lane weights in VGPRs (prescaled, as f2 pairs) ----
  f2 wi0[16], wh0[8], wi1[8], wh1[8];
  {
    const f4* p = (const f4*)(Wih0 + row * 32);
#pragma unroll
    for (int q = 0; q < 8; ++q) {
      f4 v = p[q];
      wi0[2 * q + 0] = lo2(v) * sc;
      wi0[2 * q + 1] = hi2(v) * sc;
    }
    const f4* p0 = (const f4*)(Whh0 + row * 16);
    const f4* p1 = (const f4*)(Wih1 + row * 16);
    const f4* p2 = (const f4*)(Whh1 + row * 16);
#pragma unroll
    for (int q = 0; q < 4; ++q) {
      f4 a = p0[q], bq = p1[q], cq = p2[q];
      wh0[2 * q] = lo2(a) * sc;  wh0[2 * q + 1] = hi2(a) * sc;
      wi1[2 * q] = lo2(bq) * sc; wi1[2 * q + 1] = hi2(bq) * sc;
      wh1[2 * q] = lo2(cq) * sc; wh1[2 * q + 1] = hi2(cq) * sc;
    }
  }
  const float bs0 = sc * (bih0[row] + bhh0[row]);
  const float bs1 = sc * (bih1[row] + bhh1[row]);

  const int slot = (k == 0) ? u : (16 + lane);
  float* h0slot = &lh0[w][slot];
  float* h1slot = &lh1[w][slot];

  float c0 = 0.f, c1 = 0.f;
  f2 h0p[8];
#pragma unroll
  for (int j = 0; j < 8; ++j) h0p[j] = (f2){0.f, 0.f};
  if (lane < 16) lh1[w][lane] = 0.f;  // h1[t=-1] = 0

  const float* xg = x + (size_t)b * (T_STEPS * D_INP);

  {
    const float* src = xg + lane * 4;
    __builtin_amdgcn_global_load_lds((gas1_t)(const void*)src,
                                     (las3_t)(void*)&lx[w][0][0], 16, 0, 0);
  }

#pragma unroll 1
  for (int c = 0; c < NCHUNK; ++c) {
    asm volatile("s_waitcnt vmcnt(0)" ::: "memory");
    if (c + 1 < NCHUNK) {
      const float* src = xg + (c + 1) * (CHUNK * D_INP) + lane * 4;
      __builtin_amdgcn_global_load_lds((gas1_t)(const void*)src,
                                       (las3_t)(void*)&lx[w][(c + 1) & 1][0],
                                       16, 0, 0);
    }
    const float* xp = &lx[w][c & 1][0];
#pragma unroll
    for (int tt = 0; tt < CHUNK; ++tt) {
      const float* xq = xp + tt * D_INP;
      // hoist h1[t-1] broadcast reads + Whh1 partial: independent of h0[t]
      f4 hA = *(const f4*)(&lh1[w][0]);
      f4 hB = *(const f4*)(&lh1[w][4]);
      f4 hC = *(const f4*)(&lh1[w][8]);
      f4 hD = *(const f4*)(&lh1[w][12]);
      f2 b01 = (f2){bs1, 0.f}, b23 = (f2){0.f, 0.f};
      pkfma(b01, wh1[0], lo2(hA));  pkfma(b23, wh1[1], hi2(hA));
      pkfma(b01, wh1[2], lo2(hB));  pkfma(b23, wh1[3], hi2(hB));
      pkfma(b01, wh1[4], lo2(hC));  pkfma(b23, wh1[5], hi2(hC));
      pkfma(b01, wh1[6], lo2(hD));  pkfma(b23, wh1[7], hi2(hD));
      // ======== layer 0 ========
      f2 a01 = (f2){bs0, 0.f}, a23 = (f2){0.f, 0.f};
#pragma unroll
      for (int q = 0; q < 8; ++q) {
        f4 v = *(const f4*)(xq + 4 * q);   // ds_read_b128 broadcast
        pkfma(a01, wi0[2 * q + 0], lo2(v));
        pkfma(a23, wi0[2 * q + 1], hi2(v));
      }
#pragma unroll
      for (int q = 0; q < 4; ++q) {
        pkfma(a01, wh0[2 * q + 0], h0p[2 * q + 0]);
        pkfma(a23, wh0[2 * q + 1], h0p[2 * q + 1]);
      }
      f2 asum = pkadd(a01, a23);
      float gs = asum.x + asum.y;
      float av = fmaf(mA, frcp(1.f + fexp2(gs)), aA);
      float fv = qbcast<1>(av), gv = qbcast<2>(av), ov = qbcast<3>(av);
      c0 = fmaf(fv, c0, av * gv);
      float th = fmaf(2.f, frcp(1.f + fexp2(TANHK * c0)), -1.f);
      float h0n = ov * th;
      *h0slot = h0n;                        // compact write of h0[t]
#pragma unroll
      for (int q = 0; q < 4; ++q) {         // broadcast h0[t]; reused at t+1
        f4 hv = *(const f4*)(&lh0[w][4 * q]);
        h0p[2 * q + 0] = lo2(hv);
        h0p[2 * q + 1] = hi2(hv);
      }
      // ======== layer 1 tail ========
#pragma unroll
      for (int q = 0; q < 4; ++q) {
        pkfma(b01, wi1[2 * q + 0], h0p[2 * q + 0]);
        pkfma(b23, wi1[2 * q + 1], h0p[2 * q + 1]);
      }
      f2 bsum = pkadd(b01, b23);
      float gs1 = bsum.x + bsum.y;
      float av1 = fmaf(mA, frcp(1.f + fexp2(gs1)), aA);
      float fv1 = qbcast<1>(av1), gv1 = qbcast<2>(av1), ov1 = qbcast<3>(av1);
      c1 = fmaf(fv1, c1, av1 * gv1);
      float th1 = fmaf(2.f, frcp(1.f + fexp2(TANHK * c1)), -1.f);
      float h1n = ov1 * th1;
      *h1slot = h1n;
    }
  }

  // ======== head: y = relu(h1_T @ fc1^T + b1) @ fc2^T + b2 ========
  float h1f[16];
#pragma unroll
  for (int q = 0; q < 4; ++q) {
    f4 hv = *(const f4*)(&lh1[w][4 * q]);
#pragma unroll
    for (int r = 0; r < 4; ++r) h1f[4 * q + r] = hv[r];
  }
  float rr = 0.f;
  if (lane < 8) {
    float acc = fc1b[lane];
#pragma unroll
    for (int j = 0; j < 16; ++j) acc = fmaf(fc1w[lane * 16 + j], h1f[j], acc);
    rr = fmaxf(acc, 0.f) * fc2w[lane];
  }
  rr += __shfl_xor(rr, 1, 64);
  rr += __shfl_xor(rr, 2, 64);
  rr += __shfl_xor(rr, 4, 64);
  if (lane == 0) out[b] = rr + fc2b[0];
}

extern "C" void kernel_launch(void* const* d_in, const int* in_sizes, int n_in,
                              void* d_out, int out_size, void* d_ws, size_t ws_size,
                              hipStream_t stream) {
  (void)in_sizes; (void)n_in; (void)d_ws; (void)ws_size; (void)out_size;
  const float* x    = (const float*)d_in[0];
  const float* Wih0 = (const float*)d_in[1];
  const float* Whh0 = (const float*)d_in[2];
  const float* bih0 = (const float*)d_in[3];
  const float* bhh0 = (const float*)d_in[4];
  const float* Wih1 = (const float*)d_in[5];
  const float* Whh1 = (const float*)d_in[6];
  const float* bih1 = (const float*)d_in[7];
  const float* bhh1 = (const float*)d_in[8];
  const float* fc1w = (const float*)d_in[9];
  const float* fc1b = (const float*)d_in[10];
  const float* fc2w = (const float*)d_in[11];
  const float* fc2b = (const float*)d_in[12];
  lstm2_pk<<<dim3(1024), dim3(256), 0, stream>>>(
      x, Wih0, Whh0, bih0, bhh0, Wih1, Whh1, bih1, bhh1,
      fc1w, fc1b, fc2w, fc2b, (float*)d_out);
}